// Round 10
// baseline (2687.301 us; speedup 1.0000x reference)
//
#include <hip/hip_runtime.h>
#include <hip/hip_bf16.h>

// Shapes (fixed by the reference): B=32, T=2048, D=512, H=128.
#define Bx 32
#define Tt 2048
#define Dd 512
#define Hh 128
#define PROW 520   // padded panel row (floats)

typedef __attribute__((ext_vector_type(8))) short short8;   // 8 bf16 (4 VGPR)
typedef __attribute__((ext_vector_type(4))) float f32x4;    // MFMA C/D

static __device__ __forceinline__ short f2bf(float f) {
    __hip_bfloat16 h = __float2bfloat16(f);
    return *reinterpret_cast<short*>(&h);
}
static __device__ __forceinline__ float sigm(float x) {
    return 1.f / (1.f + __expf(-x));
}
template<int CTRL>
static __device__ __forceinline__ float dpp_add(float v) {
    return v + __int_as_float(__builtin_amdgcn_update_dpp(
        0, __float_as_int(v), CTRL, 0xF, 0xF, true));
}

// barrier that does NOT drain vmcnt
#define BARRIER_LGKM() asm volatile("s_waitcnt lgkmcnt(0)\n\ts_barrier" ::: "memory")

// async global->LDS, 16B per lane
typedef __attribute__((address_space(1))) const void gas_void;
typedef __attribute__((address_space(3))) void las_void;
static __device__ __forceinline__ void gl_lds16(const float* g, float* l) {
    __builtin_amdgcn_global_load_lds((gas_void*)g, (las_void*)l, 16, 0, 0);
}

// ---------------------------------------------------------------------------
// Phase 1: G = x @ [W|...] + bias (bias folded into acc init). Verified R9.
// ---------------------------------------------------------------------------
__global__ __launch_bounds__(512, 2) void gemm_xw_mfma(
    const float* __restrict__ X,
    const float* __restrict__ W0, const float* __restrict__ W1,
    const float* __restrict__ W2, const float* __restrict__ W3,
    const float* __restrict__ B0, const float* __restrict__ B1,
    const float* __restrict__ B2, const float* __restrict__ B3,
    float* __restrict__ G)
{
    __shared__ __align__(16) short As[128][40];
    __shared__ __align__(16) short Bs[512][40];

    const int tid  = threadIdx.x;
    const int m0   = blockIdx.x * 128;
    const int lane = tid & 63;
    const int w    = tid >> 6;
    const int wr   = w >> 2, wc = w & 3;
    const int l15  = lane & 15, kb = lane >> 4;

    const int bn   = tid;
    const int gate = bn >> 7;
    const int j    = bn & 127;
    const float* __restrict__ Wg = (gate == 0) ? W0 : (gate == 1) ? W1 : (gate == 2) ? W2 : W3;

    const int am = tid >> 2;
    const int ak = (tid & 3) * 8;

    const float* __restrict__ Bg = (wc == 0) ? B0 : (wc == 1) ? B1 : (wc == 2) ? B2 : B3;
    f32x4 acc[4][8];
    #pragma unroll
    for (int nt = 0; nt < 8; ++nt) {
        const float bv = Bg[nt * 16 + l15];
        #pragma unroll
        for (int mt = 0; mt < 4; ++mt)
            acc[mt][nt] = (f32x4){bv, bv, bv, bv};
    }

    for (int k0 = 0; k0 < Dd; k0 += 32) {
        {
            const float4* xp = (const float4*)&X[(size_t)(m0 + am) * Dd + k0 + ak];
            float4 v0 = xp[0], v1 = xp[1];
            short8 s;
            s[0] = f2bf(v0.x); s[1] = f2bf(v0.y); s[2] = f2bf(v0.z); s[3] = f2bf(v0.w);
            s[4] = f2bf(v1.x); s[5] = f2bf(v1.y); s[6] = f2bf(v1.z); s[7] = f2bf(v1.w);
            *(short8*)&As[am][ak] = s;
        }
        #pragma unroll
        for (int rc = 0; rc < 4; ++rc) {
            float v[8];
            #pragma unroll
            for (int r = 0; r < 8; ++r)
                v[r] = Wg[(size_t)(k0 + rc * 8 + r) * Hh + j];
            short8 s;
            #pragma unroll
            for (int r = 0; r < 8; ++r) s[r] = f2bf(v[r]);
            *(short8*)&Bs[bn][rc * 8] = s;
        }
        __syncthreads();

        short8 a[4], b[8];
        #pragma unroll
        for (int mt = 0; mt < 4; ++mt)
            a[mt] = *(const short8*)&As[wr * 64 + mt * 16 + l15][kb * 8];
        #pragma unroll
        for (int nt = 0; nt < 8; ++nt)
            b[nt] = *(const short8*)&Bs[wc * 128 + nt * 16 + l15][kb * 8];
        #pragma unroll
        for (int mt = 0; mt < 4; ++mt)
            #pragma unroll
            for (int nt = 0; nt < 8; ++nt)
                acc[mt][nt] = __builtin_amdgcn_mfma_f32_16x16x32_bf16(a[mt], b[nt], acc[mt][nt], 0, 0, 0);
        __syncthreads();
    }

    #pragma unroll
    for (int mt = 0; mt < 4; ++mt)
        #pragma unroll
        for (int nt = 0; nt < 8; ++nt)
            #pragma unroll
            for (int r = 0; r < 4; ++r)
                G[(size_t)(m0 + wr * 64 + mt * 16 + kb * 4 + r) * 512 + wc * 128 + nt * 16 + l15]
                    = acc[mt][nt][r];
}

// ---------------------------------------------------------------------------
// Phase 2: MFMA scan, all-gates-per-wave j-tiling.
// Wave w owns j-tile j0 = w*16 (16 cols) across ALL 4 gates:
//   D[j][batch] = mfma(A = U^T (M=j), B = h^T (N=batch)), 4 gate-tiles x K=4.
// C layout (verified m89/R9): col = lane&15 -> batch, row = kb*4+reg -> j.
// Thread (l15<4 = batch, kb) holds ALL 4 gates at its 4 j's -> LN norm,
// sigmoid, c/h update fully thread-local. Cross-wave traffic = LN stats only
// (per-thread partial write, wave-0 fold, broadcast read).
// ---------------------------------------------------------------------------
__global__ __launch_bounds__(512, 1) void lstm_scan_mfma(
    const float* __restrict__ G,
    const float* __restrict__ Uf, const float* __restrict__ Ui,
    const float* __restrict__ Uo, const float* __restrict__ Uc,
    const float* __restrict__ lnfg, const float* __restrict__ lnfb,
    const float* __restrict__ lnig, const float* __restrict__ lnib,
    const float* __restrict__ lnog, const float* __restrict__ lnob,
    const float* __restrict__ lncg, const float* __restrict__ lncb,
    const float* __restrict__ h0, const float* __restrict__ c0,
    const int* __restrict__ zmask,
    float* __restrict__ out, float* __restrict__ hT)
{
    const int tid  = threadIdx.x;
    const int lane = tid & 63;
    const int w    = tid >> 6;          // wave 0..7 -> j-tile
    const int b0   = blockIdx.x * 4;    // 4 batches per block

    const int l15 = lane & 15;          // MFMA col: batch (0..3 real)
    const int kb  = lane >> 4;          // 0..3: K-block / j-subtile
    const int lb  = l15 & 3;            // clamped batch
    const int j0  = w * 16;             // wave's j-tile base
    const int jj  = j0 + kb * 4;        // thread's 4 j-columns jj..jj+3

    __shared__ __align__(16) short Ap[16 * 136];     // h panel bf16 [row=b][k]
    __shared__ __align__(16) float partPS[4 * 132];  // [b][w*4+kb][g] (pad 132)
    __shared__ __align__(16) float partPQ[4 * 132];
    __shared__ __align__(16) float2 stats[16];       // [b*4+g] = (S, Q)
    __shared__ __align__(16) float Pan[2 * 4 * 4 * PROW]; // [buf][slot][b][col]
    __shared__ unsigned short act[Tt];
    __shared__ int wsum[8], wpre[8];
    __shared__ int nact_sh;

    // ---- A fragments: U^T rows = j0+l15, all 4 gates (64 regs) ----
    short8 bfr[4][4];
    #pragma unroll
    for (int g = 0; g < 4; ++g) {
        const float* __restrict__ Ug = (g == 0) ? Uf : (g == 1) ? Ui : (g == 2) ? Uo : Uc;
        #pragma unroll
        for (int ks = 0; ks < 4; ++ks) {
            short8 v;
            #pragma unroll
            for (int r = 0; r < 8; ++r)
                v[r] = f2bf(Ug[(ks * 32 + kb * 8 + r) * Hh + j0 + l15]);
            bfr[g][ks] = v;
        }
    }

    // ---- per-thread LN consts at jj..jj+3, all gates ----
    f32x4 gam[4], bet[4];
    gam[0] = *(const f32x4*)&lnfg[jj]; bet[0] = *(const f32x4*)&lnfb[jj];
    gam[1] = *(const f32x4*)&lnig[jj]; bet[1] = *(const f32x4*)&lnib[jj];
    gam[2] = *(const f32x4*)&lnog[jj]; bet[2] = *(const f32x4*)&lnob[jj];
    gam[3] = *(const f32x4*)&lncg[jj]; bet[3] = *(const f32x4*)&lncb[jj];

    // ---- state: 4 c/h values per thread (batch lb, cols jj..jj+3) ----
    f32x4 cv = *(const f32x4*)&c0[(b0 + lb) * Hh + jj];
    f32x4 hv = *(const f32x4*)&h0[(b0 + lb) * Hh + jj];

    for (int i = tid; i < 16 * 136; i += 512) Ap[i] = 0;
    __syncthreads();
    if (l15 < 4) {
        short hp[4];
        #pragma unroll
        for (int r = 0; r < 4; ++r) hp[r] = f2bf(hv[r]);
        *(short4*)&Ap[l15 * 136 + jj] = *(short4*)hp;
    }

    // ---- parallel active-list build ----
    {
        const int base_t = tid * 4;
        const int f0 = (zmask[base_t] == 0), f1 = (zmask[base_t + 1] == 0);
        const int f2 = (zmask[base_t + 2] == 0), f3 = (zmask[base_t + 3] == 0);
        const int cnt = f0 + f1 + f2 + f3;
        int scan = cnt;
        #pragma unroll
        for (int off = 1; off <= 32; off <<= 1) {
            int v = __shfl_up(scan, off);
            if (lane >= off) scan += v;
        }
        if (lane == 63) wsum[w] = scan;
        __syncthreads();
        if (tid == 0) {
            int s = 0;
            #pragma unroll
            for (int i = 0; i < 8; ++i) { wpre[i] = s; s += wsum[i]; }
            nact_sh = s;
        }
        __syncthreads();
        int pos = wpre[w] + scan - cnt;
        if (f0) act[pos++] = (unsigned short)(base_t);
        if (f1) act[pos++] = (unsigned short)(base_t + 1);
        if (f2) act[pos++] = (unsigned short)(base_t + 2);
        if (f3) act[pos++] = (unsigned short)(base_t + 3);
    }
    __syncthreads();
    const int nact = nact_sh;

    // ---- G panel staging (verified R7-R9) ----
    auto stage_panel = [&](int kp, int buf) {
        #pragma unroll
        for (int si = 0; si < 2; ++si) {
            const int s    = w * 2 + si;
            const int slot = s >> 2;
            const int bb   = s & 3;
            const int kidx = kp + slot;
            if (kidx < nact) {
                const int tt = (int)act[kidx];
                const float* src = &G[((size_t)(b0 + bb) * Tt + tt) * 512];
                float* dst = &Pan[((buf * 4 + slot) * 4 + bb) * PROW];
                gl_lds16(src + lane * 4, dst);
                gl_lds16(src + 256 + lane * 4, dst + 256);
            }
        }
    };

    int cur = 0;
    stage_panel(0, 0);
    asm volatile("s_waitcnt vmcnt(0)" ::: "memory");
    __syncthreads();

    auto lstm_step = [&](int kidx, int slot) {
        const int t_ = (int)act[kidx];

        // ============ Phase A: MFMA + per-thread LN partials ============
        // B operand (h): lane col = batch l15 (rows 4..15 of Ap are zero)
        short8 a0 = *(const short8*)&Ap[l15 * 136 +  0 + kb * 8];
        short8 a1 = *(const short8*)&Ap[l15 * 136 + 32 + kb * 8];
        short8 a2 = *(const short8*)&Ap[l15 * 136 + 64 + kb * 8];
        short8 a3 = *(const short8*)&Ap[l15 * 136 + 96 + kb * 8];

        // C init = G+bias from panel: batch lb, gate g, cols jj..jj+3
        const int pbase = ((cur * 4 + slot) * 4 + lb) * PROW;
        f32x4 C0 = *(const f32x4*)&Pan[pbase +   0 + jj];
        f32x4 C1 = *(const f32x4*)&Pan[pbase + 128 + jj];
        f32x4 C2 = *(const f32x4*)&Pan[pbase + 256 + jj];
        f32x4 C3 = *(const f32x4*)&Pan[pbase + 384 + jj];

        C0 = __builtin_amdgcn_mfma_f32_16x16x32_bf16(bfr[0][0], a0, C0, 0, 0, 0);
        C1 = __builtin_amdgcn_mfma_f32_16x16x32_bf16(bfr[1][0], a0, C1, 0, 0, 0);
        C2 = __builtin_amdgcn_mfma_f32_16x16x32_bf16(bfr[2][0], a0, C2, 0, 0, 0);
        C3 = __builtin_amdgcn_mfma_f32_16x16x32_bf16(bfr[3][0], a0, C3, 0, 0, 0);
        C0 = __builtin_amdgcn_mfma_f32_16x16x32_bf16(bfr[0][1], a1, C0, 0, 0, 0);
        C1 = __builtin_amdgcn_mfma_f32_16x16x32_bf16(bfr[1][1], a1, C1, 0, 0, 0);
        C2 = __builtin_amdgcn_mfma_f32_16x16x32_bf16(bfr[2][1], a1, C2, 0, 0, 0);
        C3 = __builtin_amdgcn_mfma_f32_16x16x32_bf16(bfr[3][1], a1, C3, 0, 0, 0);
        C0 = __builtin_amdgcn_mfma_f32_16x16x32_bf16(bfr[0][2], a2, C0, 0, 0, 0);
        C1 = __builtin_amdgcn_mfma_f32_16x16x32_bf16(bfr[1][2], a2, C1, 0, 0, 0);
        C2 = __builtin_amdgcn_mfma_f32_16x16x32_bf16(bfr[2][2], a2, C2, 0, 0, 0);
        C3 = __builtin_amdgcn_mfma_f32_16x16x32_bf16(bfr[3][2], a2, C3, 0, 0, 0);
        C0 = __builtin_amdgcn_mfma_f32_16x16x32_bf16(bfr[0][3], a3, C0, 0, 0, 0);
        C1 = __builtin_amdgcn_mfma_f32_16x16x32_bf16(bfr[1][3], a3, C1, 0, 0, 0);
        C2 = __builtin_amdgcn_mfma_f32_16x16x32_bf16(bfr[2][3], a3, C2, 0, 0, 0);
        C3 = __builtin_amdgcn_mfma_f32_16x16x32_bf16(bfr[3][3], a3, C3, 0, 0, 0);

        // per-thread LN partials (batch l15, 4 j's) per gate
        f32x4 psv, pqv;
        psv[0] = (C0[0] + C0[1]) + (C0[2] + C0[3]);
        psv[1] = (C1[0] + C1[1]) + (C1[2] + C1[3]);
        psv[2] = (C2[0] + C2[1]) + (C2[2] + C2[3]);
        psv[3] = (C3[0] + C3[1]) + (C3[2] + C3[3]);
        pqv[0] = C0[0]*C0[0] + C0[1]*C0[1] + C0[2]*C0[2] + C0[3]*C0[3];
        pqv[1] = C1[0]*C1[0] + C1[1]*C1[1] + C1[2]*C1[2] + C1[3]*C1[3];
        pqv[2] = C2[0]*C2[0] + C2[1]*C2[1] + C2[2]*C2[2] + C2[3]*C2[3];
        pqv[3] = C3[0]*C3[0] + C3[1]*C3[1] + C3[2]*C3[2] + C3[3]*C3[3];
        if (l15 < 4) {
            const int pa = l15 * 132 + (w * 4 + kb) * 4;
            *(f32x4*)&partPS[pa] = psv;
            *(f32x4*)&partPQ[pa] = pqv;
        }
        BARRIER_LGKM();

        // ============ stage 2: wave 0 folds 32 partials per (b,g) ============
        if (w == 0) {
            const int bg = lane >> 2;        // (b*4+g)
            const int bq = bg >> 2, gq = bg & 3;
            const int ch = lane & 3;
            float S = 0.f, Q = 0.f;
            #pragma unroll
            for (int i = 0; i < 8; ++i) {
                const int pa = bq * 132 + (ch * 8 + i) * 4 + gq;
                S += partPS[pa];
                Q += partPQ[pa];
            }
            S = dpp_add<0xB1>(S); S = dpp_add<0x4E>(S);
            Q = dpp_add<0xB1>(Q); Q = dpp_add<0x4E>(Q);
            if (ch == 0) stats[bg] = make_float2(S, Q);
        }
        BARRIER_LGKM();

        // ============ Phase B: thread-local LN + sigmoid + c/h ============
        if (l15 < 4) {
            f32x4 st01 = *(const f32x4*)&stats[l15 * 4];      // S0,Q0,S1,Q1
            f32x4 st23 = *(const f32x4*)&stats[l15 * 4 + 2];  // S2,Q2,S3,Q3
            const float mu0 = st01[0] * (1.f/128.f), r0 = rsqrtf(st01[1]*(1.f/128.f) - mu0*mu0 + 1e-5f);
            const float mu1 = st01[2] * (1.f/128.f), r1 = rsqrtf(st01[3]*(1.f/128.f) - mu1*mu1 + 1e-5f);
            const float mu2 = st23[0] * (1.f/128.f), r2 = rsqrtf(st23[1]*(1.f/128.f) - mu2*mu2 + 1e-5f);
            const float mu3 = st23[2] * (1.f/128.f), r3 = rsqrtf(st23[3]*(1.f/128.f) - mu3*mu3 + 1e-5f);
            f32x4 hnew;
            #pragma unroll
            for (int r = 0; r < 4; ++r) {
                const float gf  = sigm((C0[r] - mu0) * r0 * gam[0][r] + bet[0][r]);
                const float gi  = sigm((C1[r] - mu1) * r1 * gam[1][r] + bet[1][r]);
                const float go  = sigm((C2[r] - mu2) * r2 * gam[2][r] + bet[2][r]);
                const float gch = sigm((C3[r] - mu3) * r3 * gam[3][r] + bet[3][r]);
                cv[r] = gf * cv[r] + gi * gch;
                hnew[r] = go * sigm(cv[r]);          // NB: sigmoid, not tanh
            }
            hv = hnew;
            short hp[4];
            #pragma unroll
            for (int r = 0; r < 4; ++r) hp[r] = f2bf(hv[r]);
            *(short4*)&Ap[l15 * 136 + jj] = *(short4*)hp;
            float4 ho = make_float4(hv[0], hv[1], hv[2], hv[3]);
            *(float4*)&out[((size_t)(b0 + l15) * Tt + t_) * Hh + jj] = ho;
        }
    };

    for (int kp = 0; kp < nact; kp += 4) {
        stage_panel(kp + 4, cur ^ 1);                // issue next panel early
        const int lim = (nact - kp < 4) ? (nact - kp) : 4;
        #pragma unroll
        for (int sl = 0; sl < 4; ++sl) {
            if (sl < lim) {
                lstm_step(kp + sl, sl);
                if (sl == 3)                          // once per group: drain DMA
                    asm volatile("s_waitcnt vmcnt(0)" ::: "memory");
                BARRIER_LGKM();
            }
        }
        cur ^= 1;
    }

    if (l15 < 4) {
        float4 ho = make_float4(hv[0], hv[1], hv[2], hv[3]);
        *(float4*)&hT[(b0 + l15) * Hh + jj] = ho;
    }
}

// ---------------------------------------------------------------------------
// Phase 3: fill zoneout timesteps (verified R7-R9).
// ---------------------------------------------------------------------------
__global__ __launch_bounds__(512) void fill_zoneout(
    const int* __restrict__ zmask, const float* __restrict__ h0,
    float* __restrict__ out)
{
    const int t = blockIdx.x;
    if (zmask[t] == 0) return;            // active: scan wrote it
    int s = t - 1;
    while (s >= 0 && zmask[s] != 0) --s;
    const int tid = threadIdx.x;
    for (int idx = tid; idx < Bx * Hh; idx += 512) {
        const int b = idx >> 7, j = idx & 127;
        const float v = (s >= 0) ? out[((size_t)b * Tt + s) * Hh + j]
                                 : h0[b * Hh + j];
        out[((size_t)b * Tt + t) * Hh + j] = v;
    }
}

// ---------------------------------------------------------------------------
extern "C" void kernel_launch(void* const* d_in, const int* in_sizes, int n_in,
                              void* d_out, int out_size, void* d_ws, size_t ws_size,
                              hipStream_t stream)
{
    const float* x   = (const float*)d_in[0];
    const float* W_f = (const float*)d_in[1];
    const float* W_i = (const float*)d_in[2];
    const float* W_o = (const float*)d_in[3];
    const float* W_c = (const float*)d_in[4];
    const float* U_f = (const float*)d_in[5];
    const float* U_i = (const float*)d_in[6];
    const float* U_o = (const float*)d_in[7];
    const float* U_c = (const float*)d_in[8];
    const float* b_f = (const float*)d_in[9];
    const float* b_i = (const float*)d_in[10];
    const float* b_o = (const float*)d_in[11];
    const float* b_c = (const float*)d_in[12];
    const float* ln_f_g = (const float*)d_in[13];
    const float* ln_f_b = (const float*)d_in[14];
    const float* ln_i_g = (const float*)d_in[15];
    const float* ln_i_b = (const float*)d_in[16];
    const float* ln_o_g = (const float*)d_in[17];
    const float* ln_o_b = (const float*)d_in[18];
    const float* ln_c_g = (const float*)d_in[19];
    const float* ln_c_b = (const float*)d_in[20];
    const float* h0  = (const float*)d_in[21];
    const float* c0  = (const float*)d_in[22];
    const int*   zm  = (const int*)d_in[23];

    float* out = (float*)d_out;                       // [B, T, H]
    float* hT  = out + (size_t)Bx * Tt * Hh;          // [B, H]
    float* G   = (float*)d_ws;                        // [B*T, 512] = 128 MiB

    gemm_xw_mfma<<<(Bx * Tt) / 128, 512, 0, stream>>>(x, W_f, W_i, W_o, W_c,
                                                      b_f, b_i, b_o, b_c, G);

    lstm_scan_mfma<<<8, 512, 0, stream>>>(G, U_f, U_i, U_o, U_c,
                                          ln_f_g, ln_f_b, ln_i_g, ln_i_b,
                                          ln_o_g, ln_o_b, ln_c_g, ln_c_b,
                                          h0, c0, zm, out, hT);

    fill_zoneout<<<Tt, 512, 0, stream>>>(zm, h0, out);
}

// Round 11
// 1615.419 us; speedup vs baseline: 1.6635x; 1.6635x over previous
//
#include <hip/hip_runtime.h>
#include <hip/hip_bf16.h>

// Shapes (fixed by the reference): B=32, T=2048, D=512, H=128.
#define Bx 32
#define Tt 2048
#define Dd 512
#define Hh 128
#define APS 152   // Ap row stride in shorts: 304B = 76 dw, 76%32=12 -> ~2-way banks

typedef __attribute__((ext_vector_type(8))) short short8;   // 8 bf16 (4 VGPR)
typedef __attribute__((ext_vector_type(4))) float f32x4;    // MFMA C/D

static __device__ __forceinline__ short f2bf(float f) {
    __hip_bfloat16 h = __float2bfloat16(f);
    return *reinterpret_cast<short*>(&h);
}
static __device__ __forceinline__ float sigm(float x) {
    return 1.f / (1.f + __expf(-x));
}

// 16-lane-row DPP add (VALU-speed cross-lane). Stages xor1, xor2, ror4, ror8
// + one ds_swizzle xor16 give a full 32-lane allreduce (verified R5).
template<int CTRL>
static __device__ __forceinline__ float dpp_add(float v) {
    return v + __int_as_float(__builtin_amdgcn_update_dpp(
        0, __float_as_int(v), CTRL, 0xF, 0xF, true));
}
static __device__ __forceinline__ float swz_xor16_add(float v) {
    return v + __int_as_float(__builtin_amdgcn_ds_swizzle(__float_as_int(v), 0x401F));
}

// barrier that does NOT drain vmcnt (keeps G prefetch / out stores in flight)
#define BARRIER_LGKM() asm volatile("s_waitcnt lgkmcnt(0)\n\ts_barrier" ::: "memory")

// ---------------------------------------------------------------------------
// Phase 1: G = x @ [W_f|W_i|W_o|W_c], bf16 MFMA.  (verified R4-R10, ~90us)
// ---------------------------------------------------------------------------
__global__ __launch_bounds__(512, 2) void gemm_xw_mfma(
    const float* __restrict__ X,
    const float* __restrict__ W0, const float* __restrict__ W1,
    const float* __restrict__ W2, const float* __restrict__ W3,
    float* __restrict__ G)
{
    __shared__ __align__(16) short As[128][40];
    __shared__ __align__(16) short Bs[512][40];

    const int tid  = threadIdx.x;
    const int m0   = blockIdx.x * 128;
    const int lane = tid & 63;
    const int w    = tid >> 6;
    const int wr   = w >> 2, wc = w & 3;
    const int l15  = lane & 15, kb = lane >> 4;

    const int bn   = tid;
    const int gate = bn >> 7;
    const int j    = bn & 127;
    const float* __restrict__ Wg = (gate == 0) ? W0 : (gate == 1) ? W1 : (gate == 2) ? W2 : W3;

    const int am = tid >> 2;
    const int ak = (tid & 3) * 8;

    f32x4 acc[4][8];
    #pragma unroll
    for (int mt = 0; mt < 4; ++mt)
        #pragma unroll
        for (int nt = 0; nt < 8; ++nt)
            acc[mt][nt] = (f32x4){0.f, 0.f, 0.f, 0.f};

    for (int k0 = 0; k0 < Dd; k0 += 32) {
        {
            const float4* xp = (const float4*)&X[(size_t)(m0 + am) * Dd + k0 + ak];
            float4 v0 = xp[0], v1 = xp[1];
            short8 s;
            s[0] = f2bf(v0.x); s[1] = f2bf(v0.y); s[2] = f2bf(v0.z); s[3] = f2bf(v0.w);
            s[4] = f2bf(v1.x); s[5] = f2bf(v1.y); s[6] = f2bf(v1.z); s[7] = f2bf(v1.w);
            *(short8*)&As[am][ak] = s;
        }
        #pragma unroll
        for (int rc = 0; rc < 4; ++rc) {
            float v[8];
            #pragma unroll
            for (int r = 0; r < 8; ++r)
                v[r] = Wg[(size_t)(k0 + rc * 8 + r) * Hh + j];
            short8 s;
            #pragma unroll
            for (int r = 0; r < 8; ++r) s[r] = f2bf(v[r]);
            *(short8*)&Bs[bn][rc * 8] = s;
        }
        __syncthreads();

        short8 a[4], b[8];
        #pragma unroll
        for (int mt = 0; mt < 4; ++mt)
            a[mt] = *(const short8*)&As[wr * 64 + mt * 16 + l15][kb * 8];
        #pragma unroll
        for (int nt = 0; nt < 8; ++nt)
            b[nt] = *(const short8*)&Bs[wc * 128 + nt * 16 + l15][kb * 8];
        #pragma unroll
        for (int mt = 0; mt < 4; ++mt)
            #pragma unroll
            for (int nt = 0; nt < 8; ++nt)
                acc[mt][nt] = __builtin_amdgcn_mfma_f32_16x16x32_bf16(a[mt], b[nt], acc[mt][nt], 0, 0, 0);
        __syncthreads();
    }

    #pragma unroll
    for (int mt = 0; mt < 4; ++mt)
        #pragma unroll
        for (int nt = 0; nt < 8; ++nt)
            #pragma unroll
            for (int r = 0; r < 4; ++r)
                G[(size_t)(m0 + wr * 64 + mt * 16 + kb * 4 + r) * 512 + wc * 128 + nt * 16 + l15]
                    = acc[mt][nt][r];
}

// ---------------------------------------------------------------------------
// Phase 2: MFMA scan — exact R5 structure (best measured: 1528us), with the
// Ap stride changed 136 -> 152 shorts to break the 4-way bank conflict on
// the per-step a-fragment ds_read_b128s.
// ---------------------------------------------------------------------------
__global__ __launch_bounds__(512, 1) void lstm_scan_mfma(
    const float* __restrict__ G,
    const float* __restrict__ Uf, const float* __restrict__ Ui,
    const float* __restrict__ Uo, const float* __restrict__ Uc,
    const float* __restrict__ bf_, const float* __restrict__ bi_,
    const float* __restrict__ bo_, const float* __restrict__ bc_,
    const float* __restrict__ lnfg, const float* __restrict__ lnfb,
    const float* __restrict__ lnig, const float* __restrict__ lnib,
    const float* __restrict__ lnog, const float* __restrict__ lnob,
    const float* __restrict__ lncg, const float* __restrict__ lncb,
    const float* __restrict__ h0, const float* __restrict__ c0,
    const int* __restrict__ zmask,
    float* __restrict__ out, float* __restrict__ hT)
{
    const int tid  = threadIdx.x;
    const int lane = tid & 63;
    const int w    = tid >> 6;          // wave 0..7
    const int b0   = blockIdx.x * 4;    // 4 batches per block

    __shared__ __align__(16) short Ap[16 * APS];     // h panel bf16 [row=b][k]
    __shared__ __align__(16) float ST[512 * 10];     // S/gates transposed [col][b]
    __shared__ unsigned short act[Tt];
    __shared__ int wsum[8], wpre[8];
    __shared__ int nact_sh;

    // ---- B fragments: U columns in bf16 (wave w -> gate w>>1, 64 cols) ----
    const int gate = w >> 1;
    const float* __restrict__ Ug = (gate == 0) ? Uf : (gate == 1) ? Ui : (gate == 2) ? Uo : Uc;
    const int n0  = w * 64;
    const int l15 = lane & 15;
    const int kb  = lane >> 4;

    short8 bfr[4][4];
    #pragma unroll
    for (int nt = 0; nt < 4; ++nt) {
        const int jloc = (n0 & 127) + nt * 16 + l15;
        #pragma unroll
        for (int ks = 0; ks < 4; ++ks) {
            short8 v;
            #pragma unroll
            for (int r = 0; r < 8; ++r)
                v[r] = f2bf(Ug[(ks * 32 + kb * 8 + r) * Hh + jloc]);
            bfr[nt][ks] = v;
        }
    }

    // ---- LN-thread constants: thread = (rowL = bL*4+gL, cl) ----
    const int rowL = tid >> 5;
    const int bL   = rowL >> 2;
    const int gL   = rowL & 3;
    const int cl   = tid & 31;
    const float* lnGp = (gL == 0) ? lnfg : (gL == 1) ? lnig : (gL == 2) ? lnog : lncg;
    const float* lnBp = (gL == 0) ? lnfb : (gL == 1) ? lnib : (gL == 2) ? lnob : lncb;
    const float* bgp  = (gL == 0) ? bf_  : (gL == 1) ? bi_  : (gL == 2) ? bo_  : bc_;
    float lgam[4], lbet[4], lbias[4];
    #pragma unroll
    for (int kk = 0; kk < 4; ++kk) {
        const int jc = cl + 32 * kk;
        lgam[kk] = lnGp[jc]; lbet[kk] = lnBp[jc]; lbias[kk] = bgp[jc];
    }

    // ---- owner state: thread = (ob = tid>>7, oj = tid&127) ----
    const int ob = tid >> 7;
    const int oj = tid & 127;
    float hval = h0[(b0 + ob) * Hh + oj];
    float cval = c0[(b0 + ob) * Hh + oj];

    for (int i = tid; i < 16 * APS; i += 512) Ap[i] = 0;
    __syncthreads();
    Ap[ob * APS + oj] = f2bf(hval);

    // ---- parallel active-list build ----
    {
        const int base_t = tid * 4;
        const int f0 = (zmask[base_t] == 0), f1 = (zmask[base_t + 1] == 0);
        const int f2 = (zmask[base_t + 2] == 0), f3 = (zmask[base_t + 3] == 0);
        const int cnt = f0 + f1 + f2 + f3;
        int scan = cnt;
        #pragma unroll
        for (int off = 1; off <= 32; off <<= 1) {
            int v = __shfl_up(scan, off);
            if (lane >= off) scan += v;
        }
        if (lane == 63) wsum[w] = scan;
        __syncthreads();
        if (tid == 0) {
            int s = 0;
            #pragma unroll
            for (int i = 0; i < 8; ++i) { wpre[i] = s; s += wsum[i]; }
            nact_sh = s;
        }
        __syncthreads();
        int pos = wpre[w] + scan - cnt;
        if (f0) act[pos++] = (unsigned short)(base_t);
        if (f1) act[pos++] = (unsigned short)(base_t + 1);
        if (f2) act[pos++] = (unsigned short)(base_t + 2);
        if (f3) act[pos++] = (unsigned short)(base_t + 3);
    }
    __syncthreads();
    const int nact = nact_sh;

    const int firstA = (nact > 0) ? (int)act[0] : Tt;
    for (int tt = 0; tt < firstA; ++tt)
        out[((size_t)(b0 + ob) * Tt + tt) * Hh + oj] = hval;

// G prefetch for step t into DST[4] (C-layout: reg r = batch b0+r)
#define PREFETCH_G(tq, DST)                                                       \
    do {                                                                          \
        const int _t = (tq);                                                      \
        DST##0[0] = G[((size_t)(b0 + 0) * Tt + _t) * 512 + n0 +  0 + l15];        \
        DST##0[1] = G[((size_t)(b0 + 1) * Tt + _t) * 512 + n0 +  0 + l15];        \
        DST##0[2] = G[((size_t)(b0 + 2) * Tt + _t) * 512 + n0 +  0 + l15];        \
        DST##0[3] = G[((size_t)(b0 + 3) * Tt + _t) * 512 + n0 +  0 + l15];        \
        DST##1[0] = G[((size_t)(b0 + 0) * Tt + _t) * 512 + n0 + 16 + l15];        \
        DST##1[1] = G[((size_t)(b0 + 1) * Tt + _t) * 512 + n0 + 16 + l15];        \
        DST##1[2] = G[((size_t)(b0 + 2) * Tt + _t) * 512 + n0 + 16 + l15];        \
        DST##1[3] = G[((size_t)(b0 + 3) * Tt + _t) * 512 + n0 + 16 + l15];        \
        DST##2[0] = G[((size_t)(b0 + 0) * Tt + _t) * 512 + n0 + 32 + l15];        \
        DST##2[1] = G[((size_t)(b0 + 1) * Tt + _t) * 512 + n0 + 32 + l15];        \
        DST##2[2] = G[((size_t)(b0 + 2) * Tt + _t) * 512 + n0 + 32 + l15];        \
        DST##2[3] = G[((size_t)(b0 + 3) * Tt + _t) * 512 + n0 + 32 + l15];        \
        DST##3[0] = G[((size_t)(b0 + 0) * Tt + _t) * 512 + n0 + 48 + l15];        \
        DST##3[1] = G[((size_t)(b0 + 1) * Tt + _t) * 512 + n0 + 48 + l15];        \
        DST##3[2] = G[((size_t)(b0 + 2) * Tt + _t) * 512 + n0 + 48 + l15];        \
        DST##3[3] = G[((size_t)(b0 + 3) * Tt + _t) * 512 + n0 + 48 + l15];        \
    } while (0)

    f32x4 gA0, gA1, gA2, gA3, gB0, gB1, gB2, gB3;
    if (nact > 0) PREFETCH_G((int)act[0], gA);
    if (nact > 1) PREFETCH_G((int)act[1], gB);

#define LSTM_STEP(KK, CUR)                                                        \
    do {                                                                          \
        const int _k  = (KK);                                                     \
        const int t   = (int)act[_k];                                             \
        const int t2  = (_k + 1 < nact) ? (int)act[_k + 1] : Tt;                  \
        short8 a0 = *(const short8*)&Ap[l15 * APS +  0 + kb * 8];                 \
        short8 a1 = *(const short8*)&Ap[l15 * APS + 32 + kb * 8];                 \
        short8 a2 = *(const short8*)&Ap[l15 * APS + 64 + kb * 8];                 \
        short8 a3 = *(const short8*)&Ap[l15 * APS + 96 + kb * 8];                 \
        f32x4 C0 = CUR##0, C1 = CUR##1, C2_ = CUR##2, C3 = CUR##3;                \
        f32x4 D0 = {0,0,0,0}, D1 = {0,0,0,0}, D2 = {0,0,0,0}, D3 = {0,0,0,0};     \
        C0  = __builtin_amdgcn_mfma_f32_16x16x32_bf16(a0, bfr[0][0], C0,  0,0,0); \
        C1  = __builtin_amdgcn_mfma_f32_16x16x32_bf16(a0, bfr[1][0], C1,  0,0,0); \
        C2_ = __builtin_amdgcn_mfma_f32_16x16x32_bf16(a0, bfr[2][0], C2_, 0,0,0); \
        C3  = __builtin_amdgcn_mfma_f32_16x16x32_bf16(a0, bfr[3][0], C3,  0,0,0); \
        D0  = __builtin_amdgcn_mfma_f32_16x16x32_bf16(a2, bfr[0][2], D0,  0,0,0); \
        D1  = __builtin_amdgcn_mfma_f32_16x16x32_bf16(a2, bfr[1][2], D1,  0,0,0); \
        D2  = __builtin_amdgcn_mfma_f32_16x16x32_bf16(a2, bfr[2][2], D2,  0,0,0); \
        D3  = __builtin_amdgcn_mfma_f32_16x16x32_bf16(a2, bfr[3][2], D3,  0,0,0); \
        C0  = __builtin_amdgcn_mfma_f32_16x16x32_bf16(a1, bfr[0][1], C0,  0,0,0); \
        C1  = __builtin_amdgcn_mfma_f32_16x16x32_bf16(a1, bfr[1][1], C1,  0,0,0); \
        C2_ = __builtin_amdgcn_mfma_f32_16x16x32_bf16(a1, bfr[2][1], C2_, 0,0,0); \
        C3  = __builtin_amdgcn_mfma_f32_16x16x32_bf16(a1, bfr[3][1], C3,  0,0,0); \
        D0  = __builtin_amdgcn_mfma_f32_16x16x32_bf16(a3, bfr[0][3], D0,  0,0,0); \
        D1  = __builtin_amdgcn_mfma_f32_16x16x32_bf16(a3, bfr[1][3], D1,  0,0,0); \
        D2  = __builtin_amdgcn_mfma_f32_16x16x32_bf16(a3, bfr[2][3], D2,  0,0,0); \
        D3  = __builtin_amdgcn_mfma_f32_16x16x32_bf16(a3, bfr[3][3], D3,  0,0,0); \
        if (_k + 2 < nact) PREFETCH_G((int)act[_k + 2], CUR);                     \
        if (lane < 16) {                                                          \
            *(float2*)&ST[(n0 +  0 + l15) * 10]     = make_float2(C0[0]+D0[0], C0[1]+D0[1]); \
            *(float2*)&ST[(n0 +  0 + l15) * 10 + 2] = make_float2(C0[2]+D0[2], C0[3]+D0[3]); \
            *(float2*)&ST[(n0 + 16 + l15) * 10]     = make_float2(C1[0]+D1[0], C1[1]+D1[1]); \
            *(float2*)&ST[(n0 + 16 + l15) * 10 + 2] = make_float2(C1[2]+D1[2], C1[3]+D1[3]); \
            *(float2*)&ST[(n0 + 32 + l15) * 10]     = make_float2(C2_[0]+D2[0], C2_[1]+D2[1]); \
            *(float2*)&ST[(n0 + 32 + l15) * 10 + 2] = make_float2(C2_[2]+D2[2], C2_[3]+D2[3]); \
            *(float2*)&ST[(n0 + 48 + l15) * 10]     = make_float2(C3[0]+D3[0], C3[1]+D3[1]); \
            *(float2*)&ST[(n0 + 48 + l15) * 10 + 2] = make_float2(C3[2]+D3[2], C3[3]+D3[3]); \
        }                                                                         \
        BARRIER_LGKM();                                                           \
        float s0_ = ST[(gL * 128 + cl +  0) * 10 + bL] + lbias[0];                \
        float s1_ = ST[(gL * 128 + cl + 32) * 10 + bL] + lbias[1];                \
        float s2_ = ST[(gL * 128 + cl + 64) * 10 + bL] + lbias[2];                \
        float s3_ = ST[(gL * 128 + cl + 96) * 10 + bL] + lbias[3];                \
        float sm = (s0_ + s1_) + (s2_ + s3_);                                     \
        float sq = s0_*s0_ + s1_*s1_ + s2_*s2_ + s3_*s3_;                         \
        sm = dpp_add<0xB1>(sm);  sq = dpp_add<0xB1>(sq);                          \
        sm = dpp_add<0x4E>(sm);  sq = dpp_add<0x4E>(sq);                          \
        sm = dpp_add<0x124>(sm); sq = dpp_add<0x124>(sq);                         \
        sm = dpp_add<0x128>(sm); sq = dpp_add<0x128>(sq);                         \
        sm = swz_xor16_add(sm);  sq = swz_xor16_add(sq);                          \
        const float mu   = sm * (1.f / 128.f);                                    \
        const float rstd = rsqrtf(sq * (1.f / 128.f) - mu * mu + 1e-5f);          \
        ST[(gL * 128 + cl +  0) * 10 + bL] = sigm((s0_ - mu) * rstd * lgam[0] + lbet[0]); \
        ST[(gL * 128 + cl + 32) * 10 + bL] = sigm((s1_ - mu) * rstd * lgam[1] + lbet[1]); \
        ST[(gL * 128 + cl + 64) * 10 + bL] = sigm((s2_ - mu) * rstd * lgam[2] + lbet[2]); \
        ST[(gL * 128 + cl + 96) * 10 + bL] = sigm((s3_ - mu) * rstd * lgam[3] + lbet[3]); \
        BARRIER_LGKM();                                                           \
        const float gf  = ST[(0   + oj) * 10 + ob];                               \
        const float gi  = ST[(128 + oj) * 10 + ob];                               \
        const float go  = ST[(256 + oj) * 10 + ob];                               \
        const float gch = ST[(384 + oj) * 10 + ob];                               \
        cval = gf * cval + gi * gch;                                              \
        hval = go * sigm(cval);                                                   \
        Ap[ob * APS + oj] = f2bf(hval);                                           \
        for (int tt = t; tt < t2; ++tt)                                           \
            out[((size_t)(b0 + ob) * Tt + tt) * Hh + oj] = hval;                  \
        BARRIER_LGKM();                                                           \
    } while (0)

    for (int k = 0; k < nact; k += 2) {
        LSTM_STEP(k, gA);
        if (k + 1 < nact) LSTM_STEP(k + 1, gB);
    }

    hT[(b0 + ob) * Hh + oj] = hval;
#undef LSTM_STEP
#undef PREFETCH_G
}

// ---------------------------------------------------------------------------
extern "C" void kernel_launch(void* const* d_in, const int* in_sizes, int n_in,
                              void* d_out, int out_size, void* d_ws, size_t ws_size,
                              hipStream_t stream)
{
    const float* x   = (const float*)d_in[0];
    const float* W_f = (const float*)d_in[1];
    const float* W_i = (const float*)d_in[2];
    const float* W_o = (const float*)d_in[3];
    const float* W_c = (const float*)d_in[4];
    const float* U_f = (const float*)d_in[5];
    const float* U_i = (const float*)d_in[6];
    const float* U_o = (const float*)d_in[7];
    const float* U_c = (const float*)d_in[8];
    const float* b_f = (const float*)d_in[9];
    const float* b_i = (const float*)d_in[10];
    const float* b_o = (const float*)d_in[11];
    const float* b_c = (const float*)d_in[12];
    const float* ln_f_g = (const float*)d_in[13];
    const float* ln_f_b = (const float*)d_in[14];
    const float* ln_i_g = (const float*)d_in[15];
    const float* ln_i_b = (const float*)d_in[16];
    const float* ln_o_g = (const float*)d_in[17];
    const float* ln_o_b = (const float*)d_in[18];
    const float* ln_c_g = (const float*)d_in[19];
    const float* ln_c_b = (const float*)d_in[20];
    const float* h0  = (const float*)d_in[21];
    const float* c0  = (const float*)d_in[22];
    const int*   zm  = (const int*)d_in[23];

    float* out = (float*)d_out;                       // [B, T, H]
    float* hT  = out + (size_t)Bx * Tt * Hh;          // [B, H]
    float* G   = (float*)d_ws;                        // [B*T, 512] = 128 MiB

    gemm_xw_mfma<<<(Bx * Tt) / 128, 512, 0, stream>>>(x, W_f, W_i, W_o, W_c, G);

    lstm_scan_mfma<<<8, 512, 0, stream>>>(G, U_f, U_i, U_o, U_c,
                                          b_f, b_i, b_o, b_c,
                                          ln_f_g, ln_f_b, ln_i_g, ln_i_b,
                                          ln_o_g, ln_o_b, ln_c_g, ln_c_b,
                                          h0, c0, zm, out, hT);
}

// Round 12
// 1613.895 us; speedup vs baseline: 1.6651x; 1.0009x over previous
//
#include <hip/hip_runtime.h>
#include <hip/hip_bf16.h>

// Shapes (fixed by the reference): B=32, T=2048, D=512, H=128.
#define Bx 32
#define Tt 2048
#define Dd 512
#define Hh 128
#define APS 152    // Ap row stride (shorts)
#define PROW 520   // padded panel row (floats)
#define SGS 528    // SLN gate stride (floats) = 4*132

typedef __attribute__((ext_vector_type(8))) short short8;   // 8 bf16 (4 VGPR)
typedef __attribute__((ext_vector_type(4))) float f32x4;    // MFMA C/D

static __device__ __forceinline__ short f2bf(float f) {
    __hip_bfloat16 h = __float2bfloat16(f);
    return *reinterpret_cast<short*>(&h);
}
static __device__ __forceinline__ float sigm(float x) {
    return 1.f / (1.f + __expf(-x));
}
static __device__ __forceinline__ float swz_xor16_add(float v) {
    return v + __int_as_float(__builtin_amdgcn_ds_swizzle(__float_as_int(v), 0x401F));
}

// barrier that does NOT drain vmcnt
#define BARRIER_LGKM() asm volatile("s_waitcnt lgkmcnt(0)\n\ts_barrier" ::: "memory")

// async global->LDS, 16B per lane
typedef __attribute__((address_space(1))) const void gas_void;
typedef __attribute__((address_space(3))) void las_void;
static __device__ __forceinline__ void gl_lds16(const float* g, float* l) {
    __builtin_amdgcn_global_load_lds((gas_void*)g, (las_void*)l, 16, 0, 0);
}

// ---------------------------------------------------------------------------
// Phase 1: G = x @ [W|...] + bias (bias folded into acc init). Verified R9/R10.
// ---------------------------------------------------------------------------
__global__ __launch_bounds__(512, 2) void gemm_xw_mfma(
    const float* __restrict__ X,
    const float* __restrict__ W0, const float* __restrict__ W1,
    const float* __restrict__ W2, const float* __restrict__ W3,
    const float* __restrict__ B0, const float* __restrict__ B1,
    const float* __restrict__ B2, const float* __restrict__ B3,
    float* __restrict__ G)
{
    __shared__ __align__(16) short As[128][40];
    __shared__ __align__(16) short Bs[512][40];

    const int tid  = threadIdx.x;
    const int m0   = blockIdx.x * 128;
    const int lane = tid & 63;
    const int w    = tid >> 6;
    const int wr   = w >> 2, wc = w & 3;
    const int l15  = lane & 15, kb = lane >> 4;

    const int bn   = tid;
    const int gate = bn >> 7;
    const int j    = bn & 127;
    const float* __restrict__ Wg = (gate == 0) ? W0 : (gate == 1) ? W1 : (gate == 2) ? W2 : W3;

    const int am = tid >> 2;
    const int ak = (tid & 3) * 8;

    const float* __restrict__ Bg = (wc == 0) ? B0 : (wc == 1) ? B1 : (wc == 2) ? B2 : B3;
    f32x4 acc[4][8];
    #pragma unroll
    for (int nt = 0; nt < 8; ++nt) {
        const float bv = Bg[nt * 16 + l15];
        #pragma unroll
        for (int mt = 0; mt < 4; ++mt)
            acc[mt][nt] = (f32x4){bv, bv, bv, bv};
    }

    for (int k0 = 0; k0 < Dd; k0 += 32) {
        {
            const float4* xp = (const float4*)&X[(size_t)(m0 + am) * Dd + k0 + ak];
            float4 v0 = xp[0], v1 = xp[1];
            short8 s;
            s[0] = f2bf(v0.x); s[1] = f2bf(v0.y); s[2] = f2bf(v0.z); s[3] = f2bf(v0.w);
            s[4] = f2bf(v1.x); s[5] = f2bf(v1.y); s[6] = f2bf(v1.z); s[7] = f2bf(v1.w);
            *(short8*)&As[am][ak] = s;
        }
        #pragma unroll
        for (int rc = 0; rc < 4; ++rc) {
            float v[8];
            #pragma unroll
            for (int r = 0; r < 8; ++r)
                v[r] = Wg[(size_t)(k0 + rc * 8 + r) * Hh + j];
            short8 s;
            #pragma unroll
            for (int r = 0; r < 8; ++r) s[r] = f2bf(v[r]);
            *(short8*)&Bs[bn][rc * 8] = s;
        }
        __syncthreads();

        short8 a[4], b[8];
        #pragma unroll
        for (int mt = 0; mt < 4; ++mt)
            a[mt] = *(const short8*)&As[wr * 64 + mt * 16 + l15][kb * 8];
        #pragma unroll
        for (int nt = 0; nt < 8; ++nt)
            b[nt] = *(const short8*)&Bs[wc * 128 + nt * 16 + l15][kb * 8];
        #pragma unroll
        for (int mt = 0; mt < 4; ++mt)
            #pragma unroll
            for (int nt = 0; nt < 8; ++nt)
                acc[mt][nt] = __builtin_amdgcn_mfma_f32_16x16x32_bf16(a[mt], b[nt], acc[mt][nt], 0, 0, 0);
        __syncthreads();
    }

    #pragma unroll
    for (int mt = 0; mt < 4; ++mt)
        #pragma unroll
        for (int nt = 0; nt < 8; ++nt)
            #pragma unroll
            for (int r = 0; r < 4; ++r)
                G[(size_t)(m0 + wr * 64 + mt * 16 + kb * 4 + r) * 512 + wc * 128 + nt * 16 + l15]
                    = acc[mt][nt][r];
}

// ---------------------------------------------------------------------------
// Phase 2: MFMA scan, 4 waves (1/SIMD), gate-per-wave, 8 blocks x 256 thr.
// Wave w = gate w: 32 MFMAs cover S[128 j][4 b] (operand-swapped, layout
// verified R9/R10: C col = lane&15 -> batch, row = kb*4+reg -> j).
// LN is fully in-wave (xor16 swizzle + shfl_xor 32); normalized pre-acts go
// to LDS once; owner threads (wave=batch, lane=j) finish sigmoid + c/h.
// 2 barriers per step.
// ---------------------------------------------------------------------------
__global__ __launch_bounds__(256, 1) void lstm_scan_mfma(
    const float* __restrict__ G,
    const float* __restrict__ Uf, const float* __restrict__ Ui,
    const float* __restrict__ Uo, const float* __restrict__ Uc,
    const float* __restrict__ lnfg, const float* __restrict__ lnfb,
    const float* __restrict__ lnig, const float* __restrict__ lnib,
    const float* __restrict__ lnog, const float* __restrict__ lnob,
    const float* __restrict__ lncg, const float* __restrict__ lncb,
    const float* __restrict__ h0, const float* __restrict__ c0,
    const int* __restrict__ zmask,
    float* __restrict__ out, float* __restrict__ hT)
{
    const int tid  = threadIdx.x;
    const int lane = tid & 63;
    const int w    = tid >> 6;          // wave 0..3 = gate (phase A) / batch (phase B)
    const int b0   = blockIdx.x * 4;    // 4 batches per block
    const int l15  = lane & 15;
    const int kb   = lane >> 4;

    __shared__ __align__(16) short Ap[16 * APS];           // h panel bf16 [b][k]
    __shared__ __align__(16) float SLN[4 * SGS];           // [g][b][j] normalized
    __shared__ __align__(16) float Pan[2 * 4 * 4 * PROW];  // [buf][slot][b][col]
    __shared__ unsigned short act[Tt];
    __shared__ int wsum[4], wpre[4];
    __shared__ int nact_sh;

    // ---- A fragments: wave's gate, ALL 128 j (8 nt-tiles x 4 k-steps) ----
    const float* __restrict__ Ug = (w == 0) ? Uf : (w == 1) ? Ui : (w == 2) ? Uo : Uc;
    short8 bfr[8][4];
    #pragma unroll
    for (int nt = 0; nt < 8; ++nt) {
        #pragma unroll
        for (int ks = 0; ks < 4; ++ks) {
            short8 v;
            #pragma unroll
            for (int r = 0; r < 8; ++r)
                v[r] = f2bf(Ug[(ks * 32 + kb * 8 + r) * Hh + nt * 16 + l15]);
            bfr[nt][ks] = v;
        }
    }

    // ---- owner constants: thread = (batch w, cols j1 = lane, j2 = lane+64) ----
    const int j1 = lane, j2 = lane + 64;
    const float gF1 = lnfg[j1], bF1 = lnfb[j1], gF2 = lnfg[j2], bF2 = lnfb[j2];
    const float gI1 = lnig[j1], bI1 = lnib[j1], gI2 = lnig[j2], bI2 = lnib[j2];
    const float gO1 = lnog[j1], bO1 = lnob[j1], gO2 = lnog[j2], bO2 = lnob[j2];
    const float gC1 = lncg[j1], bC1 = lncb[j1], gC2 = lncg[j2], bC2 = lncb[j2];

    float hv0 = h0[(b0 + w) * Hh + j1];
    float hv1 = h0[(b0 + w) * Hh + j2];
    float cv0 = c0[(b0 + w) * Hh + j1];
    float cv1 = c0[(b0 + w) * Hh + j2];

    for (int i = tid; i < 16 * APS; i += 256) Ap[i] = 0;
    __syncthreads();
    Ap[w * APS + j1] = f2bf(hv0);
    Ap[w * APS + j2] = f2bf(hv1);

    // ---- parallel active-list build (8 flags per thread) ----
    {
        const int base_t = tid * 8;
        int fl[8], cnt = 0;
        #pragma unroll
        for (int i = 0; i < 8; ++i) { fl[i] = (zmask[base_t + i] == 0); cnt += fl[i]; }
        int scan = cnt;
        #pragma unroll
        for (int off = 1; off <= 32; off <<= 1) {
            int v = __shfl_up(scan, off);
            if (lane >= off) scan += v;
        }
        if (lane == 63) wsum[w] = scan;
        __syncthreads();
        if (tid == 0) {
            int s = 0;
            #pragma unroll
            for (int i = 0; i < 4; ++i) { wpre[i] = s; s += wsum[i]; }
            nact_sh = s;
        }
        __syncthreads();
        int pos = wpre[w] + scan - cnt;
        #pragma unroll
        for (int i = 0; i < 8; ++i)
            if (fl[i]) act[pos++] = (unsigned short)(base_t + i);
    }
    __syncthreads();
    const int nact = nact_sh;

    // leading zoneout steps: out = h0
    const int firstA = (nact > 0) ? (int)act[0] : Tt;
    for (int tt = 0; tt < firstA; ++tt) {
        out[((size_t)(b0 + w) * Tt + tt) * Hh + j1] = hv0;
        out[((size_t)(b0 + w) * Tt + tt) * Hh + j2] = hv1;
    }

    // ---- G panel staging: wave w loads 4 slices (slot s>>2, batch s&3) ----
    auto stage_panel = [&](int kp, int buf) {
        #pragma unroll
        for (int si = 0; si < 4; ++si) {
            const int s    = w * 4 + si;
            const int slot = s >> 2;
            const int bb   = s & 3;
            const int kidx = kp + slot;
            if (kidx < nact) {
                const int tt = (int)act[kidx];
                const float* src = &G[((size_t)(b0 + bb) * Tt + tt) * 512];
                float* dst = &Pan[((buf * 4 + slot) * 4 + bb) * PROW];
                gl_lds16(src + lane * 4, dst);
                gl_lds16(src + 256 + lane * 4, dst + 256);
            }
        }
    };

    int cur = 0;
    stage_panel(0, 0);
    asm volatile("s_waitcnt vmcnt(0)" ::: "memory");
    __syncthreads();

    const int lb = l15 & 3;   // clamped batch for panel reads

    auto lstm_step = [&](int kidx, int slot) {
        const int t_ = (int)act[kidx];

        // ============ Phase A (wave = gate) ============
        short8 a0 = *(const short8*)&Ap[l15 * APS +  0 + kb * 8];
        short8 a1 = *(const short8*)&Ap[l15 * APS + 32 + kb * 8];
        short8 a2 = *(const short8*)&Ap[l15 * APS + 64 + kb * 8];
        short8 a3 = *(const short8*)&Ap[l15 * APS + 96 + kb * 8];

        // C init = G+bias: batch lb, gate w, j = nt*16 + kb*4 .. +3
        const int pbase = ((cur * 4 + slot) * 4 + lb) * PROW + w * 128 + kb * 4;
        f32x4 Cv[8];
        #pragma unroll
        for (int nt = 0; nt < 8; ++nt)
            Cv[nt] = *(const f32x4*)&Pan[pbase + nt * 16];

        #pragma unroll
        for (int nt = 0; nt < 8; ++nt)
            Cv[nt] = __builtin_amdgcn_mfma_f32_16x16x32_bf16(bfr[nt][0], a0, Cv[nt], 0, 0, 0);
        #pragma unroll
        for (int nt = 0; nt < 8; ++nt)
            Cv[nt] = __builtin_amdgcn_mfma_f32_16x16x32_bf16(bfr[nt][1], a1, Cv[nt], 0, 0, 0);
        #pragma unroll
        for (int nt = 0; nt < 8; ++nt)
            Cv[nt] = __builtin_amdgcn_mfma_f32_16x16x32_bf16(bfr[nt][2], a2, Cv[nt], 0, 0, 0);
        #pragma unroll
        for (int nt = 0; nt < 8; ++nt)
            Cv[nt] = __builtin_amdgcn_mfma_f32_16x16x32_bf16(bfr[nt][3], a3, Cv[nt], 0, 0, 0);

        // in-wave LN stats: lane holds 32 j-values of (batch l15, gate w)
        float sm = 0.f, sq = 0.f;
        #pragma unroll
        for (int nt = 0; nt < 8; ++nt)
            #pragma unroll
            for (int r = 0; r < 4; ++r) {
                sm += Cv[nt][r];
                sq = fmaf(Cv[nt][r], Cv[nt][r], sq);
            }
        sm = swz_xor16_add(sm);          // fold kb 0<->1, 2<->3
        sq = swz_xor16_add(sq);
        sm += __shfl_xor(sm, 32);        // fold kb {0,1} <-> {2,3}
        sq += __shfl_xor(sq, 32);
        const float mu   = sm * (1.f / 128.f);
        const float rstd = rsqrtf(sq * (1.f / 128.f) - mu * mu + 1e-5f);
        const float na = rstd, nc = -mu * rstd;
        #pragma unroll
        for (int nt = 0; nt < 8; ++nt)
            #pragma unroll
            for (int r = 0; r < 4; ++r)
                Cv[nt][r] = fmaf(Cv[nt][r], na, nc);

        if (l15 < 4) {
            #pragma unroll
            for (int nt = 0; nt < 8; ++nt)
                *(f32x4*)&SLN[w * SGS + l15 * 132 + nt * 16 + kb * 4] = Cv[nt];
        }
        BARRIER_LGKM();

        // ============ Phase B (wave = batch w, lane = j) ============
        {
            const int sb = w * 132;
            const float nf0 = SLN[0 * SGS + sb + j1], nf1 = SLN[0 * SGS + sb + j2];
            const float ni0 = SLN[1 * SGS + sb + j1], ni1 = SLN[1 * SGS + sb + j2];
            const float no0 = SLN[2 * SGS + sb + j1], no1 = SLN[2 * SGS + sb + j2];
            const float nc0 = SLN[3 * SGS + sb + j1], nc1 = SLN[3 * SGS + sb + j2];
            const float f0 = sigm(fmaf(nf0, gF1, bF1));
            const float i0 = sigm(fmaf(ni0, gI1, bI1));
            const float o0 = sigm(fmaf(no0, gO1, bO1));
            const float g0 = sigm(fmaf(nc0, gC1, bC1));
            const float f1 = sigm(fmaf(nf1, gF2, bF2));
            const float i1 = sigm(fmaf(ni1, gI2, bI2));
            const float o1 = sigm(fmaf(no1, gO2, bO2));
            const float g1 = sigm(fmaf(nc1, gC2, bC2));
            cv0 = f0 * cv0 + i0 * g0;
            hv0 = o0 * sigm(cv0);                    // NB: sigmoid, not tanh
            cv1 = f1 * cv1 + i1 * g1;
            hv1 = o1 * sigm(cv1);
            Ap[w * APS + j1] = f2bf(hv0);
            Ap[w * APS + j2] = f2bf(hv1);
            out[((size_t)(b0 + w) * Tt + t_) * Hh + j1] = hv0;
            out[((size_t)(b0 + w) * Tt + t_) * Hh + j2] = hv1;
        }
        BARRIER_LGKM();
    };

    for (int kp = 0; kp < nact; kp += 4) {
        stage_panel(kp + 4, cur ^ 1);                // issue next panel early
        const int lim = (nact - kp < 4) ? (nact - kp) : 4;
        #pragma unroll
        for (int sl = 0; sl < 4; ++sl) {
            if (sl < lim) {
                lstm_step(kp + sl, sl);
                if (sl == 3)                          // once per group: drain DMA
                    asm volatile("s_waitcnt vmcnt(0)" ::: "memory");
            }
        }
        cur ^= 1;
    }

    hT[(b0 + w) * Hh + j1] = hv0;
    hT[(b0 + w) * Hh + j2] = hv1;
}

// ---------------------------------------------------------------------------
// Phase 3: fill zoneout timesteps (verified R7-R9).
// ---------------------------------------------------------------------------
__global__ __launch_bounds__(512) void fill_zoneout(
    const int* __restrict__ zmask, const float* __restrict__ h0,
    float* __restrict__ out)
{
    const int t = blockIdx.x;
    if (zmask[t] == 0) return;            // active: scan wrote it
    int s = t - 1;
    while (s >= 0 && zmask[s] != 0) --s;
    const int tid = threadIdx.x;
    for (int idx = tid; idx < Bx * Hh; idx += 512) {
        const int b = idx >> 7, j = idx & 127;
        const float v = (s >= 0) ? out[((size_t)b * Tt + s) * Hh + j]
                                 : h0[b * Hh + j];
        out[((size_t)b * Tt + t) * Hh + j] = v;
    }
}

// ---------------------------------------------------------------------------
extern "C" void kernel_launch(void* const* d_in, const int* in_sizes, int n_in,
                              void* d_out, int out_size, void* d_ws, size_t ws_size,
                              hipStream_t stream)
{
    const float* x   = (const float*)d_in[0];
    const float* W_f = (const float*)d_in[1];
    const float* W_i = (const float*)d_in[2];
    const float* W_o = (const float*)d_in[3];
    const float* W_c = (const float*)d_in[4];
    const float* U_f = (const float*)d_in[5];
    const float* U_i = (const float*)d_in[6];
    const float* U_o = (const float*)d_in[7];
    const float* U_c = (const float*)d_in[8];
    const float* b_f = (const float*)d_in[9];
    const float* b_i = (const float*)d_in[10];
    const float* b_o = (const float*)d_in[11];
    const float* b_c = (const float*)d_in[12];
    const float* ln_f_g = (const float*)d_in[13];
    const float* ln_f_b = (const float*)d_in[14];
    const float* ln_i_g = (const float*)d_in[15];
    const float* ln_i_b = (const float*)d_in[16];
    const float* ln_o_g = (const float*)d_in[17];
    const float* ln_o_b = (const float*)d_in[18];
    const float* ln_c_g = (const float*)d_in[19];
    const float* ln_c_b = (const float*)d_in[20];
    const float* h0  = (const float*)d_in[21];
    const float* c0  = (const float*)d_in[22];
    const int*   zm  = (const int*)d_in[23];

    float* out = (float*)d_out;                       // [B, T, H]
    float* hT  = out + (size_t)Bx * Tt * Hh;          // [B, H]
    float* G   = (float*)d_ws;                        // [B*T, 512] = 128 MiB

    gemm_xw_mfma<<<(Bx * Tt) / 128, 512, 0, stream>>>(x, W_f, W_i, W_o, W_c,
                                                      b_f, b_i, b_o, b_c, G);

    lstm_scan_mfma<<<8, 256, 0, stream>>>(G, U_f, U_i, U_o, U_c,
                                          ln_f_g, ln_f_b, ln_i_g, ln_i_b,
                                          ln_o_g, ln_o_b, ln_c_g, ln_c_b,
                                          h0, c0, zm, out, hT);

    fill_zoneout<<<Tt, 512, 0, stream>>>(zm, h0, out);
}